// Round 11
// baseline (954.200 us; speedup 1.0000x reference)
//
#include <hip/hip_runtime.h>
#include <math.h>

#define H 256
#define D 300
#define NE 37
#define NLEAF 65536
#define NTOT 87381
#define NINT 21845
#define NICH 87380
#define PERMPAD 1184     // 37*32
#define KX 320           // padded x-K
#define KN 576           // node GEMM K = 320 + 256
#define NROWS 87424
#define NBINS 296        // 8 levels * 37 types
#define HB 120           // histogram blocks
#define CHUNK 729        // ceil(NICH/HB)

typedef __attribute__((ext_vector_type(8))) short short8;
typedef __attribute__((ext_vector_type(4))) float f32x4;

__device__ const int g_offs[10] = {0,65536,81920,86016,87040,87296,87360,87376,87380,87381};
static const int h_offs[10]     = {0,65536,81920,86016,87040,87296,87360,87376,87380,87381};

__device__ __forceinline__ float frcp(float v){ return __builtin_amdgcn_rcpf(v); }
__device__ __forceinline__ float sigm(float v){ return frcp(1.0f + __expf(-v)); }
__device__ __forceinline__ float ftanh(float v){ return 1.0f - 2.0f*frcp(__expf(2.0f*v) + 1.0f); }
__device__ __forceinline__ unsigned short f2bf(float f){
  unsigned int u = __float_as_uint(f);
  return (unsigned short)((u + 0x7fffu + ((u>>16)&1u)) >> 16);
}
__device__ __forceinline__ float bf2f(unsigned short v){ return __uint_as_float(((unsigned int)v)<<16); }
__device__ __forceinline__ short8 ld8(const unsigned short* p){ return *reinterpret_cast<const short8*>(p); }

// ---------------- conversions ------------------------------------------------
__global__ void k_convx(const float* __restrict__ x, unsigned short* __restrict__ xb)
{
  size_t total = (size_t)NROWS*KX/8;
  for (size_t v8 = (size_t)blockIdx.x*blockDim.x + threadIdx.x; v8 < total;
       v8 += (size_t)gridDim.x*blockDim.x) {
    int p = (int)(v8/40), k0 = (int)(v8%40)*8;
    short8 o;
    #pragma unroll
    for (int j=0;j<8;j++){
      int k = k0+j;
      float v = (p < NTOT && k < D) ? x[(size_t)p*D + k] : 0.f;
      o[j] = (short)f2bf(v);
    }
    *reinterpret_cast<short8*>(xb + v8*8) = o;
  }
}

__global__ void k_convw(const float* __restrict__ ioux_w, const float* __restrict__ fx_w,
                        const float* __restrict__ iouh_w, const float* __restrict__ fh_w,
                        const float* __restrict__ e2h_w,
                        unsigned short* __restrict__ WN, unsigned short* __restrict__ WE)
{
  const int TOTN = 1024*KN;
  const int TOTE = NE*512*256;
  for (int idx = blockIdx.x*blockDim.x + threadIdx.x; idx < TOTN+TOTE;
       idx += gridDim.x*blockDim.x) {
    if (idx < TOTN) {
      int n = idx/KN, k = idx%KN;
      float v = 0.f;
      if (k < D)        v = (n < 768) ? ioux_w[n*D + k] : fx_w[(n-768)*D + k];
      else if (k >= KX && n < 768) v = iouh_w[n*H + (k-KX)];
      WN[idx] = f2bf(v);
    } else {
      int r = idx - TOTN;
      int e = r/(512*256), rr = r%(512*256), n = rr>>8, k = rr&255;
      float v = (n < 256) ? e2h_w[(size_t)e*65536 + n*256 + k] : fh_w[(n-256)*256 + k];
      WE[r] = f2bf(v);
    }
  }
}

__global__ void k_bias(const float* __restrict__ ioux_b, const float* __restrict__ iouh_b,
                       const float* __restrict__ fx_b, const float* __restrict__ fh_b,
                       float* __restrict__ bias)
{
  int n = blockIdx.x*blockDim.x + threadIdx.x;
  if (n < 768)       bias[n] = ioux_b[n] + iouh_b[n];
  else if (n < 1024) bias[n] = fx_b[n-768] + fh_b[n-768];
}

// ---------------- counting sort (LDS histograms, no global atomics) ----------
__device__ __forceinline__ int level_of(int g){
  int l = 1;
  #pragma unroll
  for (int q=2;q<=8;q++) if (g >= g_offs[q]) l = q;
  return l;
}

__global__ void k_hist2(const int* __restrict__ edge_type, int* __restrict__ bhist)
{
  __shared__ int hs[NBINS];
  int b = blockIdx.x, tid = threadIdx.x;
  for (int i = tid; i < NBINS; i += 256) hs[i] = 0;
  __syncthreads();
  int t0 = b*CHUNK, t1 = min(t0+CHUNK, NICH);
  for (int t = t0 + tid; t < t1; t += 256){
    int g = NLEAF + (t>>2);
    int l = level_of(g);
    int et = edge_type[g*4 + (t&3)];
    atomicAdd(&hs[(l-1)*NE + et], 1);
  }
  __syncthreads();
  for (int i = tid; i < NBINS; i += 256) bhist[b*NBINS + i] = hs[i];
}

__global__ void k_scan(const int* __restrict__ bhist, int* __restrict__ boff,
                       int* __restrict__ ptot)
{
  __shared__ int tot[NBINS];
  __shared__ int base[NBINS];
  int tid = threadIdx.x;
  if (tid < NBINS){
    int s = 0;
    for (int b=0;b<HB;b++) s += bhist[b*NBINS + tid];
    tot[tid] = s;
  }
  __syncthreads();
  if (tid < 8){
    int acc = 0;
    for (int e=0;e<NE;e++){
      base[tid*NE + e] = acc;
      acc += ((tot[tid*NE + e] + 31)>>5)<<5;
    }
    ptot[tid] = acc;
  }
  __syncthreads();
  if (tid < NBINS){
    int run = base[tid];
    for (int b=0;b<HB;b++){
      boff[b*NBINS + tid] = run;
      run += bhist[b*NBINS + tid];
    }
  }
}

__global__ void k_scatter2(const int* __restrict__ edge_type, const int* __restrict__ boff,
                           int* __restrict__ perm)
{
  __shared__ int cnt[NBINS];
  int b = blockIdx.x, tid = threadIdx.x;
  for (int i = tid; i < NBINS; i += 256) cnt[i] = boff[b*NBINS + i];
  __syncthreads();
  int t0 = b*CHUNK, t1 = min(t0+CHUNK, NICH);
  for (int t = t0 + tid; t < t1; t += 256){
    int g = NLEAF + (t>>2);
    int l = level_of(g);
    int c = t&3;
    int et = edge_type[g*4 + c];
    int p = g - g_offs[l];
    int pos = atomicAdd(&cnt[(l-1)*NE + et], 1);
    perm[g_offs[l-1] + (l-1)*PERMPAD + pos] = 4*p + c;
  }
}

// ---------------- leaf: fused GEMM (G=3) + gates, LDS-staged ------------------
// Epilogue stages c/h tiles in LDS and writes full-line float4/short8 runs.
__launch_bounds__(256, 4)
__global__ void k_leaf_gates(const unsigned short* __restrict__ xb,
                             const unsigned short* __restrict__ WN,
                             const float* __restrict__ bias,
                             float* __restrict__ c_out,
                             unsigned short* __restrict__ h_out)
{
  __shared__ __align__(16) unsigned char smem[35840];
  unsigned short* As = (unsigned short*)smem;            // 64*40
  unsigned short* Bs = (unsigned short*)(smem + 5120);   // 384*40
  int m0 = blockIdx.x*64, n0r = blockIdx.y*128;
  int tid = threadIdx.x, lane = tid&63, wave = tid>>6;
  int wm = (wave&1)*32, wn = (wave>>1)*64;
  int ar = lane&15, kb = (lane>>4)*8;
  f32x4 acc[3][2][4] = {};

  for (int kc=0; kc<10; ++kc){
    __syncthreads();
    {
      int row = tid>>2, seg = tid&3;
      *reinterpret_cast<short8*>(&As[row*40 + seg*8]) =
        ld8(xb + (size_t)(m0+row)*KX + kc*32 + seg*8);
    }
    #pragma unroll
    for (int rep=0; rep<6; ++rep){
      int u = tid + rep*256;
      int row = u>>2, seg = u&3;        // row in [0, 384)
      int g = row>>7, rr2 = row&127;
      *reinterpret_cast<short8*>(&Bs[row*40 + seg*8]) =
        ld8(WN + (size_t)(g*256 + n0r + rr2)*KN + kc*32 + seg*8);
    }
    __syncthreads();
    short8 af[2];
    #pragma unroll
    for (int mi=0; mi<2; ++mi)
      af[mi] = ld8(&As[(wm + mi*16 + ar)*40 + kb]);
    #pragma unroll
    for (int g=0; g<3; ++g){
      #pragma unroll
      for (int nj=0; nj<4; ++nj){
        short8 bfr = ld8(&Bs[(g*128 + wn + nj*16 + ar)*40 + kb]);
        #pragma unroll
        for (int mi=0; mi<2; ++mi)
          acc[g][mi][nj] = __builtin_amdgcn_mfma_f32_16x16x32_bf16(af[mi], bfr, acc[g][mi][nj], 0,0,0);
      }
    }
  }

  int rr = (lane>>4)*4, cc = lane&15;
  unsigned short hreg[2][4][4];
  __syncthreads();                       // all waves done with Bs
  float* ct = (float*)smem;              // [64][128]
  #pragma unroll
  for (int mi=0; mi<2; ++mi){
    #pragma unroll
    for (int r=0; r<4; ++r){
      int prow = wm + mi*16 + rr + r;    // 0..63
      #pragma unroll
      for (int nj=0; nj<4; ++nj){
        int col = wn + nj*16 + cc;       // 0..127
        int i = n0r + col;
        float ig = sigm (acc[0][mi][nj][r] + bias[i]);
        float og = sigm (acc[1][mi][nj][r] + bias[256+i]);
        float uu = ftanh(acc[2][mi][nj][r] + bias[512+i]);
        float ccv = ig*uu;
        ct[prow*128 + col] = ccv;
        hreg[mi][r][nj] = f2bf(og*ftanh(ccv));
      }
    }
  }
  __syncthreads();
  #pragma unroll
  for (int it=0; it<8; ++it){
    int u = tid + it*256;                // 0..2047
    int row = u>>5, c4 = u&31;
    float4 v = *reinterpret_cast<float4*>(&ct[row*128 + c4*4]);
    *reinterpret_cast<float4*>(&c_out[(size_t)(m0+row)*H + n0r + c4*4]) = v;
  }
  __syncthreads();
  unsigned short* ht = (unsigned short*)smem;  // [64][128]
  #pragma unroll
  for (int mi=0; mi<2; ++mi){
    #pragma unroll
    for (int r=0; r<4; ++r){
      int prow = wm + mi*16 + rr + r;
      #pragma unroll
      for (int nj=0; nj<4; ++nj)
        ht[prow*128 + wn + nj*16 + cc] = hreg[mi][r][nj];
    }
  }
  __syncthreads();
  #pragma unroll
  for (int it=0; it<4; ++it){
    int u = tid + it*256;                // 0..1023
    int row = u>>4, c8 = u&15;
    short8 v = *reinterpret_cast<short8*>(&ht[row*128 + c8*8]);
    *reinterpret_cast<short8*>(&h_out[(size_t)(m0+row)*H + n0r + c8*8]) = v;
  }
}

// ---------------- per-level child GEMM: [e2h|fh] per type-block --------------
// Epilogue stages the 32x512 ybuf tile in LDS, writes 16B/lane full lines.
__launch_bounds__(256, 3)
__global__ void k_gemm_ch(const unsigned short* __restrict__ hb, const int* __restrict__ edge_type,
                          const int* __restrict__ perm, const int* __restrict__ ptot,
                          const unsigned short* __restrict__ WE,
                          unsigned short* __restrict__ ybuf, int lvl)
{
  int childbase = g_offs[lvl-1];
  int nodebase  = g_offs[lvl];
  int permbase  = childbase + (lvl-1)*PERMPAD;
  int j0 = blockIdx.x*32;
  if (j0 >= ptot[lvl-1]) return;

  __shared__ __align__(16) unsigned char smem[43520];
  unsigned short* As = (unsigned short*)smem;            // 32*40
  unsigned short* Bs = (unsigned short*)(smem + 2560);   // 512*40
  __shared__ int ks[32];
  int tid = threadIdx.x, lane = tid&63, wave = tid>>6;
  if (tid < 32) ks[tid] = perm[permbase + j0 + tid];
  __syncthreads();
  int k0 = ks[0];
  int e = edge_type[(nodebase + (k0>>2))*4 + (k0&3)];
  const unsigned short* WEe = WE + (size_t)e*512*256;
  f32x4 acc[2][8] = {};
  int ar = lane&15, kb = (lane>>4)*8;

  for (int kc=0; kc<8; ++kc){
    __syncthreads();
    if (tid < 128){
      int row = tid>>2, seg = tid&3;
      int k = ks[row];
      short8 v = {0,0,0,0,0,0,0,0};
      if (k >= 0)
        v = ld8(hb + (size_t)(childbase+k)*H + kc*32 + seg*8);
      *reinterpret_cast<short8*>(&As[row*40 + seg*8]) = v;
    }
    #pragma unroll
    for (int rep=0; rep<8; ++rep){
      int u = tid + rep*256;
      int row = u>>2, seg = u&3;
      *reinterpret_cast<short8*>(&Bs[row*40 + seg*8]) =
        ld8(WEe + (size_t)row*256 + kc*32 + seg*8);
    }
    __syncthreads();
    short8 af[2], bfr[8];
    af[0] = ld8(&As[(ar)*40 + kb]);
    af[1] = ld8(&As[(16+ar)*40 + kb]);
    #pragma unroll
    for (int j=0;j<8;j++)
      bfr[j] = ld8(&Bs[(wave*128 + j*16 + ar)*40 + kb]);
    #pragma unroll
    for (int i=0;i<2;i++)
      #pragma unroll
      for (int j=0;j<8;j++)
        acc[i][j] = __builtin_amdgcn_mfma_f32_16x16x32_bf16(af[i], bfr[j], acc[i][j], 0,0,0);
  }

  int rr = (lane>>4)*4, cc = lane&15;
  __syncthreads();                        // all waves done with As/Bs
  unsigned short* yt = (unsigned short*)smem;   // [32][512]
  #pragma unroll
  for (int i=0;i<2;i++){
    #pragma unroll
    for (int r=0;r<4;r++){
      int ml = i*16 + rr + r;
      #pragma unroll
      for (int j=0;j<8;j++)
        yt[ml*512 + wave*128 + j*16 + cc] = f2bf(acc[i][j][r]);
    }
  }
  __syncthreads();
  #pragma unroll
  for (int it=0; it<8; ++it){
    int u = tid + it*256;                 // 0..2047
    int row = u>>6, c8 = u&63;
    int k = ks[row];
    if (k >= 0){
      short8 v = *reinterpret_cast<short8*>(&yt[row*512 + c8*8]);
      *reinterpret_cast<short8*>(&ybuf[(size_t)k*512 + c8*8]) = v;
    }
  }
}

// ---------------- node gates: GEMM over K=[x(320) | sum4(ybuf)(256)] ---------
// A2-staging folds the 4-children e2h reduction into the LDS load; epilogue
// stages c/h tiles in LDS for full-line writes.
__launch_bounds__(256, 3)
__global__ void k_gates4(const unsigned short* __restrict__ xb_lvl,
                         const unsigned short* __restrict__ ybuf,
                         const unsigned short* __restrict__ WN,
                         const float* __restrict__ bias,
                         const float* __restrict__ c_child,
                         float* __restrict__ c_out,
                         unsigned short* __restrict__ h_out,
                         float* __restrict__ hroot, int rootrow, int M)
{
  __shared__ __align__(16) unsigned char smem[46080];
  unsigned short* As = (unsigned short*)smem;            // 64*40
  unsigned short* Bs = (unsigned short*)(smem + 5120);   // 512*40
  int m0 = blockIdx.x*64, n0r = blockIdx.y*128;
  int tid = threadIdx.x, lane = tid&63, wave = tid>>6;
  int wm = (wave&1)*32, wn = (wave>>1)*64;
  int ar = lane&15, kb = (lane>>4)*8;
  f32x4 acc[4][2][4] = {};

  for (int kc=0; kc<18; ++kc){
    __syncthreads();
    {
      int row = tid>>2, seg = tid&3;
      int gm = m0 + row;
      short8 v = {0,0,0,0,0,0,0,0};
      if (gm < M){
        if (kc < 10){
          v = ld8(xb_lvl + (size_t)gm*KX + kc*32 + seg*8);
        } else {
          const unsigned short* q = ybuf + (size_t)(4*gm)*512 + (kc-10)*32 + seg*8;
          short8 a0 = ld8(q), a1 = ld8(q+512), a2 = ld8(q+1024), a3 = ld8(q+1536);
          #pragma unroll
          for (int j=0;j<8;j++)
            v[j] = (short)f2bf(bf2f((unsigned short)a0[j]) + bf2f((unsigned short)a1[j])
                             + bf2f((unsigned short)a2[j]) + bf2f((unsigned short)a3[j]));
        }
      }
      *reinterpret_cast<short8*>(&As[row*40 + seg*8]) = v;
    }
    #pragma unroll
    for (int rep=0; rep<8; ++rep){
      int u = tid + rep*256;
      int row = u>>2, seg = u&3;        // row in [0, 512)
      int g = row>>7, rr2 = row&127;
      *reinterpret_cast<short8*>(&Bs[row*40 + seg*8]) =
        ld8(WN + (size_t)(g*256 + n0r + rr2)*KN + kc*32 + seg*8);
    }
    __syncthreads();
    short8 af[2];
    #pragma unroll
    for (int mi=0; mi<2; ++mi)
      af[mi] = ld8(&As[(wm + mi*16 + ar)*40 + kb]);
    #pragma unroll
    for (int g=0; g<4; ++g){
      #pragma unroll
      for (int nj=0; nj<4; ++nj){
        short8 bfr = ld8(&Bs[(g*128 + wn + nj*16 + ar)*40 + kb]);
        #pragma unroll
        for (int mi=0; mi<2; ++mi)
          acc[g][mi][nj] = __builtin_amdgcn_mfma_f32_16x16x32_bf16(af[mi], bfr, acc[g][mi][nj], 0,0,0);
      }
    }
  }

  int rr = (lane>>4)*4, cc = lane&15;
  unsigned short hreg[2][4][4];
  __syncthreads();                       // all waves done with As/Bs
  float* ct = (float*)smem;              // [64][128]
  #pragma unroll
  for (int mi=0; mi<2; ++mi){
    #pragma unroll
    for (int r=0; r<4; ++r){
      int prow = wm + mi*16 + rr + r;
      int p = m0 + prow;
      #pragma unroll
      for (int nj=0; nj<4; ++nj){
        int col = wn + nj*16 + cc;
        int i = n0r + col;
        float ig = sigm (acc[0][mi][nj][r] + bias[i]);
        float og = sigm (acc[1][mi][nj][r] + bias[256+i]);
        float uu = ftanh(acc[2][mi][nj][r] + bias[512+i]);
        float fxv = acc[3][mi][nj][r] + bias[768+i];
        float fc = 0.f;
        if (p < M){
          #pragma unroll
          for (int c=0;c<4;c++){
            int k = 4*p + c;
            fc += sigm(bf2f(ybuf[(size_t)k*512 + 256 + i]) + fxv)
                  * c_child[(size_t)k*H + i];
          }
        }
        float ccv = ig*uu + fc;
        float hh = og*ftanh(ccv);
        ct[prow*128 + col] = ccv;
        hreg[mi][r][nj] = f2bf(hh);
        if (p == rootrow) hroot[i] = hh;
      }
    }
  }
  __syncthreads();
  #pragma unroll
  for (int it=0; it<8; ++it){
    int u = tid + it*256;
    int row = u>>5, c4 = u&31;
    if (m0 + row < M){
      float4 v = *reinterpret_cast<float4*>(&ct[row*128 + c4*4]);
      *reinterpret_cast<float4*>(&c_out[(size_t)(m0+row)*H + n0r + c4*4]) = v;
    }
  }
  __syncthreads();
  unsigned short* ht = (unsigned short*)smem;  // [64][128]
  #pragma unroll
  for (int mi=0; mi<2; ++mi){
    #pragma unroll
    for (int r=0; r<4; ++r){
      int prow = wm + mi*16 + rr + r;
      #pragma unroll
      for (int nj=0; nj<4; ++nj)
        ht[prow*128 + wn + nj*16 + cc] = hreg[mi][r][nj];
    }
  }
  __syncthreads();
  #pragma unroll
  for (int it=0; it<4; ++it){
    int u = tid + it*256;
    int row = u>>4, c8 = u&15;
    if (m0 + row < M){
      short8 v = *reinterpret_cast<short8*>(&ht[row*128 + c8*8]);
      *reinterpret_cast<short8*>(&h_out[(size_t)(m0+row)*H + n0r + c8*8]) = v;
    }
  }
}

__global__ void k_out(const float* __restrict__ c_all, const float* __restrict__ hroot,
                      float* __restrict__ out)
{
  int i = threadIdx.x;
  out[i]     = c_all[(size_t)(NTOT-1)*H + i];
  out[256+i] = hroot[i];
}

// -----------------------------------------------------------------------------
extern "C" void kernel_launch(void* const* d_in, const int* in_sizes, int n_in,
                              void* d_out, int out_size, void* d_ws, size_t ws_size,
                              hipStream_t stream)
{
  const float* x        = (const float*)d_in[0];
  const int*   edge_type= (const int*)d_in[2];
  const float* e2h_w    = (const float*)d_in[5];
  const float* ioux_w   = (const float*)d_in[6];
  const float* ioux_b   = (const float*)d_in[7];
  const float* iouh_w   = (const float*)d_in[8];
  const float* iouh_b   = (const float*)d_in[9];
  const float* fx_w     = (const float*)d_in[10];
  const float* fx_b     = (const float*)d_in[11];
  const float* fh_w     = (const float*)d_in[12];
  const float* fh_b     = (const float*)d_in[13];
  float* out = (float*)d_out;

  char* ws = (char*)d_ws;
  size_t o = 0;
  auto alloc = [&](size_t bytes){ size_t r = o; o += (bytes + 255) & ~(size_t)255; return r; };
  size_t off_xb    = alloc((size_t)NROWS*KX*2);        // 56 MB bf16 x (padded)
  size_t off_hb    = alloc((size_t)NROWS*H*2);         // 44.8 MB bf16 h
  size_t off_c     = alloc((size_t)NTOT*H*4);          // 89.5 MB fp32 c
  size_t off_WN    = alloc((size_t)1024*KN*2);         // 1.2 MB
  size_t off_WE    = alloc((size_t)NE*512*256*2);      // 9.7 MB
  size_t off_bias  = alloc(1024*4);
  size_t off_ybuf  = alloc((size_t)NLEAF*512*2);       // 67 MB
  size_t off_hroot = alloc(256*4);
  size_t off_perm  = alloc((size_t)(NICH + 8*PERMPAD)*4);
  size_t off_bhist = alloc((size_t)HB*NBINS*4);
  size_t off_boff  = alloc((size_t)HB*NBINS*4);
  size_t off_ptot  = alloc(8*4);

  unsigned short* xb    = (unsigned short*)(ws + off_xb);
  unsigned short* hb    = (unsigned short*)(ws + off_hb);
  float*          c_all = (float*)(ws + off_c);
  unsigned short* WN    = (unsigned short*)(ws + off_WN);
  unsigned short* WE    = (unsigned short*)(ws + off_WE);
  float*          bias  = (float*)(ws + off_bias);
  unsigned short* ybuf  = (unsigned short*)(ws + off_ybuf);
  float*          hroot = (float*)(ws + off_hroot);
  int* perm  = (int*)(ws + off_perm);
  int* bhist = (int*)(ws + off_bhist);
  int* boff  = (int*)(ws + off_boff);
  int* ptot  = (int*)(ws + off_ptot);

  hipMemsetAsync(perm, 0xFF, (size_t)(NICH + 8*PERMPAD)*4, stream);

  k_convx<<<2048, 256, 0, stream>>>(x, xb);
  k_convw<<<2048, 256, 0, stream>>>(ioux_w, fx_w, iouh_w, fh_w, e2h_w, WN, WE);
  k_bias <<<4, 256, 0, stream>>>(ioux_b, iouh_b, fx_b, fh_b, bias);
  k_hist2   <<<HB, 256, 0, stream>>>(edge_type, bhist);
  k_scan    <<<1, 512, 0, stream>>>(bhist, boff, ptot);
  k_scatter2<<<HB, 256, 0, stream>>>(edge_type, boff, perm);

  // leaves: gates = x @ WN[iou]^T + b -> h,c fused  (M=65536, K=320)
  k_leaf_gates<<<dim3(NLEAF/64, 2), 256, 0, stream>>>(xb, WN, bias, c_all, hb);

  // levels 1..8: child GEMM (type-sorted, LDS-staged) + fused gates GEMM
  for (int l=1; l<=8; ++l){
    int s    = h_offs[l];
    int m    = h_offs[l+1] - s;
    int childbase = h_offs[l-1];
    int nch  = s - childbase;
    int nblk = (nch + NE*31 + 31)/32;
    k_gemm_ch<<<nblk, 256, 0, stream>>>(hb, edge_type, perm, ptot, WE, ybuf, l);
    k_gates4<<<dim3((m+63)/64, 2), 256, 0, stream>>>(
        xb + (size_t)s*KX, ybuf, WN, bias,
        c_all + (size_t)childbase*H,
        c_all + (size_t)s*H, hb + (size_t)s*H,
        hroot, (l==8) ? 0 : -1, m);
  }
  k_out<<<1, 256, 0, stream>>>(c_all, hroot, out);
}

// Round 12
// 578.743 us; speedup vs baseline: 1.6487x; 1.6487x over previous
//
#include <hip/hip_runtime.h>
#include <math.h>

#define H 256
#define D 300
#define NE 37
#define NLEAF 65536
#define NTOT 87381
#define NINT 21845
#define NICH 87380
#define PERMPAD 1184     // 37*32
#define KX 320           // padded x-K
#define KN 576           // node GEMM K = 320 + 256
#define NROWS 87424
#define NBINS 296        // 8 levels * 37 types
#define HB 120           // histogram blocks
#define CHUNK 729        // ceil(NICH/HB)

typedef __attribute__((ext_vector_type(8))) short short8;
typedef __attribute__((ext_vector_type(4))) float f32x4;

__device__ const int g_offs[10] = {0,65536,81920,86016,87040,87296,87360,87376,87380,87381};
static const int h_offs[10]     = {0,65536,81920,86016,87040,87296,87360,87376,87380,87381};

__device__ __forceinline__ float frcp(float v){ return __builtin_amdgcn_rcpf(v); }
__device__ __forceinline__ float sigm(float v){ return frcp(1.0f + __expf(-v)); }
__device__ __forceinline__ float ftanh(float v){ return 1.0f - 2.0f*frcp(__expf(2.0f*v) + 1.0f); }
__device__ __forceinline__ unsigned short f2bf(float f){
  unsigned int u = __float_as_uint(f);
  return (unsigned short)((u + 0x7fffu + ((u>>16)&1u)) >> 16);
}
__device__ __forceinline__ float bf2f(unsigned short v){ return __uint_as_float(((unsigned int)v)<<16); }
__device__ __forceinline__ short8 ld8(const unsigned short* p){ return *reinterpret_cast<const short8*>(p); }

// ---------------- conversions ------------------------------------------------
__global__ void k_convx(const float* __restrict__ x, unsigned short* __restrict__ xb)
{
  size_t total = (size_t)NROWS*KX/8;
  for (size_t v8 = (size_t)blockIdx.x*blockDim.x + threadIdx.x; v8 < total;
       v8 += (size_t)gridDim.x*blockDim.x) {
    int p = (int)(v8/40), k0 = (int)(v8%40)*8;
    short8 o;
    #pragma unroll
    for (int j=0;j<8;j++){
      int k = k0+j;
      float v = (p < NTOT && k < D) ? x[(size_t)p*D + k] : 0.f;
      o[j] = (short)f2bf(v);
    }
    *reinterpret_cast<short8*>(xb + v8*8) = o;
  }
}

__global__ void k_convw(const float* __restrict__ ioux_w, const float* __restrict__ fx_w,
                        const float* __restrict__ iouh_w, const float* __restrict__ fh_w,
                        const float* __restrict__ e2h_w,
                        unsigned short* __restrict__ WN, unsigned short* __restrict__ WE)
{
  const int TOTN = 1024*KN;
  const int TOTE = NE*512*256;
  for (int idx = blockIdx.x*blockDim.x + threadIdx.x; idx < TOTN+TOTE;
       idx += gridDim.x*blockDim.x) {
    if (idx < TOTN) {
      int n = idx/KN, k = idx%KN;
      float v = 0.f;
      if (k < D)        v = (n < 768) ? ioux_w[n*D + k] : fx_w[(n-768)*D + k];
      else if (k >= KX && n < 768) v = iouh_w[n*H + (k-KX)];
      WN[idx] = f2bf(v);
    } else {
      int r = idx - TOTN;
      int e = r/(512*256), rr = r%(512*256), n = rr>>8, k = rr&255;
      float v = (n < 256) ? e2h_w[(size_t)e*65536 + n*256 + k] : fh_w[(n-256)*256 + k];
      WE[r] = f2bf(v);
    }
  }
}

__global__ void k_bias(const float* __restrict__ ioux_b, const float* __restrict__ iouh_b,
                       const float* __restrict__ fx_b, const float* __restrict__ fh_b,
                       float* __restrict__ bias)
{
  int n = blockIdx.x*blockDim.x + threadIdx.x;
  if (n < 768)       bias[n] = ioux_b[n] + iouh_b[n];
  else if (n < 1024) bias[n] = fx_b[n-768] + fh_b[n-768];
}

// ---------------- counting sort (LDS histograms, no global atomics) ----------
__device__ __forceinline__ int level_of(int g){
  int l = 1;
  #pragma unroll
  for (int q=2;q<=8;q++) if (g >= g_offs[q]) l = q;
  return l;
}

__global__ void k_hist2(const int* __restrict__ edge_type, int* __restrict__ bhist)
{
  __shared__ int hs[NBINS];
  int b = blockIdx.x, tid = threadIdx.x;
  for (int i = tid; i < NBINS; i += 256) hs[i] = 0;
  __syncthreads();
  int t0 = b*CHUNK, t1 = min(t0+CHUNK, NICH);
  for (int t = t0 + tid; t < t1; t += 256){
    int g = NLEAF + (t>>2);
    int l = level_of(g);
    int et = edge_type[g*4 + (t&3)];
    atomicAdd(&hs[(l-1)*NE + et], 1);
  }
  __syncthreads();
  for (int i = tid; i < NBINS; i += 256) bhist[b*NBINS + i] = hs[i];
}

__global__ void k_scan(const int* __restrict__ bhist, int* __restrict__ boff,
                       int* __restrict__ ptot)
{
  __shared__ int tot[NBINS];
  __shared__ int base[NBINS];
  int tid = threadIdx.x;
  if (tid < NBINS){
    int s = 0;
    for (int b=0;b<HB;b++) s += bhist[b*NBINS + tid];
    tot[tid] = s;
  }
  __syncthreads();
  if (tid < 8){
    int acc = 0;
    for (int e=0;e<NE;e++){
      base[tid*NE + e] = acc;
      acc += ((tot[tid*NE + e] + 31)>>5)<<5;
    }
    ptot[tid] = acc;
  }
  __syncthreads();
  if (tid < NBINS){
    int run = base[tid];
    for (int b=0;b<HB;b++){
      boff[b*NBINS + tid] = run;
      run += bhist[b*NBINS + tid];
    }
  }
}

__global__ void k_scatter2(const int* __restrict__ edge_type, const int* __restrict__ boff,
                           int* __restrict__ perm)
{
  __shared__ int cnt[NBINS];
  int b = blockIdx.x, tid = threadIdx.x;
  for (int i = tid; i < NBINS; i += 256) cnt[i] = boff[b*NBINS + i];
  __syncthreads();
  int t0 = b*CHUNK, t1 = min(t0+CHUNK, NICH);
  for (int t = t0 + tid; t < t1; t += 256){
    int g = NLEAF + (t>>2);
    int l = level_of(g);
    int c = t&3;
    int et = edge_type[g*4 + c];
    int p = g - g_offs[l];
    int pos = atomicAdd(&cnt[(l-1)*NE + et], 1);
    perm[g_offs[l-1] + (l-1)*PERMPAD + pos] = 4*p + c;
  }
}

// ---------------- leaf: fused GEMM (G=3) + gates ------------------------------
// R12: back to __launch_bounds__(256,2) — measured A/B (R4 vs R10): 2 blocks/CU
// = 73us clean traffic; 4 blocks/CU = 158us with 3.4x L2-thrash inflation.
__launch_bounds__(256, 2)
__global__ void k_leaf_gates(const unsigned short* __restrict__ xb,
                             const unsigned short* __restrict__ WN,
                             const float* __restrict__ bias,
                             float* __restrict__ c_out,
                             unsigned short* __restrict__ h_out)
{
  __shared__ __align__(16) unsigned short As[64*40];
  __shared__ __align__(16) unsigned short Bs[3*128*40];
  int m0 = blockIdx.x*64, n0r = blockIdx.y*128;
  int tid = threadIdx.x, lane = tid&63, wave = tid>>6;
  int wm = (wave&1)*32, wn = (wave>>1)*64;
  int ar = lane&15, kb = (lane>>4)*8;
  f32x4 acc[3][2][4] = {};

  for (int kc=0; kc<10; ++kc){
    __syncthreads();
    {
      int row = tid>>2, seg = tid&3;
      *reinterpret_cast<short8*>(&As[row*40 + seg*8]) =
        ld8(xb + (size_t)(m0+row)*KX + kc*32 + seg*8);
    }
    #pragma unroll
    for (int rep=0; rep<6; ++rep){
      int u = tid + rep*256;
      int row = u>>2, seg = u&3;        // row in [0, 384)
      int g = row>>7, rr2 = row&127;
      *reinterpret_cast<short8*>(&Bs[row*40 + seg*8]) =
        ld8(WN + (size_t)(g*256 + n0r + rr2)*KN + kc*32 + seg*8);
    }
    __syncthreads();
    short8 af[2];
    #pragma unroll
    for (int mi=0; mi<2; ++mi)
      af[mi] = ld8(&As[(wm + mi*16 + ar)*40 + kb]);
    #pragma unroll
    for (int g=0; g<3; ++g){
      #pragma unroll
      for (int nj=0; nj<4; ++nj){
        short8 bfr = ld8(&Bs[(g*128 + wn + nj*16 + ar)*40 + kb]);
        #pragma unroll
        for (int mi=0; mi<2; ++mi)
          acc[g][mi][nj] = __builtin_amdgcn_mfma_f32_16x16x32_bf16(af[mi], bfr, acc[g][mi][nj], 0,0,0);
      }
    }
  }

  int rr = (lane>>4)*4, cc = lane&15;
  #pragma unroll
  for (int mi=0; mi<2; ++mi){
    #pragma unroll
    for (int r=0; r<4; ++r){
      int p = m0 + wm + mi*16 + rr + r;
      #pragma unroll
      for (int nj=0; nj<4; ++nj){
        int i = n0r + wn + nj*16 + cc;
        float ig = sigm (acc[0][mi][nj][r] + bias[i]);
        float og = sigm (acc[1][mi][nj][r] + bias[256+i]);
        float uu = ftanh(acc[2][mi][nj][r] + bias[512+i]);
        float ccv = ig*uu;
        float hh = og*ftanh(ccv);
        c_out[(size_t)p*H + i] = ccv;
        h_out[(size_t)p*H + i] = f2bf(hh);
      }
    }
  }
}

// ---------------- per-level child GEMM: [e2h|fh] per type-block --------------
__launch_bounds__(256, 3)
__global__ void k_gemm_ch(const unsigned short* __restrict__ hb, const int* __restrict__ edge_type,
                          const int* __restrict__ perm, const int* __restrict__ ptot,
                          const unsigned short* __restrict__ WE,
                          unsigned short* __restrict__ ybuf, int lvl)
{
  int childbase = g_offs[lvl-1];
  int nodebase  = g_offs[lvl];
  int permbase  = childbase + (lvl-1)*PERMPAD;
  int j0 = blockIdx.x*32;
  if (j0 >= ptot[lvl-1]) return;

  __shared__ __align__(16) unsigned short As[32*40];
  __shared__ __align__(16) unsigned short Bs[512*40];
  __shared__ int ks[32];
  int tid = threadIdx.x, lane = tid&63, wave = tid>>6;
  if (tid < 32) ks[tid] = perm[permbase + j0 + tid];
  __syncthreads();
  int k0 = ks[0];
  int e = edge_type[(nodebase + (k0>>2))*4 + (k0&3)];
  const unsigned short* WEe = WE + (size_t)e*512*256;
  f32x4 acc[2][8] = {};
  int ar = lane&15, kb = (lane>>4)*8;

  for (int kc=0; kc<8; ++kc){
    __syncthreads();
    if (tid < 128){
      int row = tid>>2, seg = tid&3;
      int k = ks[row];
      short8 v = {0,0,0,0,0,0,0,0};
      if (k >= 0)
        v = ld8(hb + (size_t)(childbase+k)*H + kc*32 + seg*8);
      *reinterpret_cast<short8*>(&As[row*40 + seg*8]) = v;
    }
    #pragma unroll
    for (int rep=0; rep<8; ++rep){
      int u = tid + rep*256;
      int row = u>>2, seg = u&3;
      *reinterpret_cast<short8*>(&Bs[row*40 + seg*8]) =
        ld8(WEe + (size_t)row*256 + kc*32 + seg*8);
    }
    __syncthreads();
    short8 af[2], bfr[8];
    af[0] = ld8(&As[(ar)*40 + kb]);
    af[1] = ld8(&As[(16+ar)*40 + kb]);
    #pragma unroll
    for (int j=0;j<8;j++)
      bfr[j] = ld8(&Bs[(wave*128 + j*16 + ar)*40 + kb]);
    #pragma unroll
    for (int i=0;i<2;i++)
      #pragma unroll
      for (int j=0;j<8;j++)
        acc[i][j] = __builtin_amdgcn_mfma_f32_16x16x32_bf16(af[i], bfr[j], acc[i][j], 0,0,0);
  }

  int rr = (lane>>4)*4, cc = lane&15;
  #pragma unroll
  for (int i=0;i<2;i++){
    #pragma unroll
    for (int r=0;r<4;r++){
      int ml = i*16 + rr + r;
      int k = ks[ml];
      if (k >= 0){
        #pragma unroll
        for (int j=0;j<8;j++){
          int n = wave*128 + j*16 + cc;
          ybuf[(size_t)k*512 + n] = f2bf(acc[i][j][r]);
        }
      }
    }
  }
}

// ---------------- node gates: GEMM over K=[x(320) | sum4(ybuf)(256)] ---------
// A2-staging folds the 4-children e2h reduction into the LDS load.
__launch_bounds__(256, 2)
__global__ void k_gates4(const unsigned short* __restrict__ xb_lvl,
                         const unsigned short* __restrict__ ybuf,
                         const unsigned short* __restrict__ WN,
                         const float* __restrict__ bias,
                         const float* __restrict__ c_child,
                         float* __restrict__ c_out,
                         unsigned short* __restrict__ h_out,
                         float* __restrict__ hroot, int rootrow, int M)
{
  __shared__ __align__(16) unsigned short As[64*40];
  __shared__ __align__(16) unsigned short Bs[4*128*40];
  int m0 = blockIdx.x*64, n0r = blockIdx.y*128;
  int tid = threadIdx.x, lane = tid&63, wave = tid>>6;
  int wm = (wave&1)*32, wn = (wave>>1)*64;
  int ar = lane&15, kb = (lane>>4)*8;
  f32x4 acc[4][2][4] = {};

  for (int kc=0; kc<18; ++kc){
    __syncthreads();
    {
      int row = tid>>2, seg = tid&3;
      int gm = m0 + row;
      short8 v = {0,0,0,0,0,0,0,0};
      if (gm < M){
        if (kc < 10){
          v = ld8(xb_lvl + (size_t)gm*KX + kc*32 + seg*8);
        } else {
          const unsigned short* q = ybuf + (size_t)(4*gm)*512 + (kc-10)*32 + seg*8;
          short8 a0 = ld8(q), a1 = ld8(q+512), a2 = ld8(q+1024), a3 = ld8(q+1536);
          #pragma unroll
          for (int j=0;j<8;j++)
            v[j] = (short)f2bf(bf2f((unsigned short)a0[j]) + bf2f((unsigned short)a1[j])
                             + bf2f((unsigned short)a2[j]) + bf2f((unsigned short)a3[j]));
        }
      }
      *reinterpret_cast<short8*>(&As[row*40 + seg*8]) = v;
    }
    #pragma unroll
    for (int rep=0; rep<8; ++rep){
      int u = tid + rep*256;
      int row = u>>2, seg = u&3;        // row in [0, 512)
      int g = row>>7, rr2 = row&127;
      *reinterpret_cast<short8*>(&Bs[row*40 + seg*8]) =
        ld8(WN + (size_t)(g*256 + n0r + rr2)*KN + kc*32 + seg*8);
    }
    __syncthreads();
    short8 af[2];
    #pragma unroll
    for (int mi=0; mi<2; ++mi)
      af[mi] = ld8(&As[(wm + mi*16 + ar)*40 + kb]);
    #pragma unroll
    for (int g=0; g<4; ++g){
      #pragma unroll
      for (int nj=0; nj<4; ++nj){
        short8 bfr = ld8(&Bs[(g*128 + wn + nj*16 + ar)*40 + kb]);
        #pragma unroll
        for (int mi=0; mi<2; ++mi)
          acc[g][mi][nj] = __builtin_amdgcn_mfma_f32_16x16x32_bf16(af[mi], bfr, acc[g][mi][nj], 0,0,0);
      }
    }
  }

  int rr = (lane>>4)*4, cc = lane&15;
  #pragma unroll
  for (int mi=0; mi<2; ++mi){
    #pragma unroll
    for (int r=0; r<4; ++r){
      int p = m0 + wm + mi*16 + rr + r;
      if (p < M){
        #pragma unroll
        for (int nj=0; nj<4; ++nj){
          int i = n0r + wn + nj*16 + cc;
          float ig = sigm (acc[0][mi][nj][r] + bias[i]);
          float og = sigm (acc[1][mi][nj][r] + bias[256+i]);
          float uu = ftanh(acc[2][mi][nj][r] + bias[512+i]);
          float fxv = acc[3][mi][nj][r] + bias[768+i];
          float fc = 0.f;
          #pragma unroll
          for (int c=0;c<4;c++){
            int k = 4*p + c;
            fc += sigm(bf2f(ybuf[(size_t)k*512 + 256 + i]) + fxv)
                  * c_child[(size_t)k*H + i];
          }
          float ccv = ig*uu + fc;
          float hh = og*ftanh(ccv);
          c_out[(size_t)p*H + i] = ccv;
          h_out[(size_t)p*H + i] = f2bf(hh);
          if (p == rootrow) hroot[i] = hh;
        }
      }
    }
  }
}

__global__ void k_out(const float* __restrict__ c_all, const float* __restrict__ hroot,
                      float* __restrict__ out)
{
  int i = threadIdx.x;
  out[i]     = c_all[(size_t)(NTOT-1)*H + i];
  out[256+i] = hroot[i];
}

// -----------------------------------------------------------------------------
extern "C" void kernel_launch(void* const* d_in, const int* in_sizes, int n_in,
                              void* d_out, int out_size, void* d_ws, size_t ws_size,
                              hipStream_t stream)
{
  const float* x        = (const float*)d_in[0];
  const int*   edge_type= (const int*)d_in[2];
  const float* e2h_w    = (const float*)d_in[5];
  const float* ioux_w   = (const float*)d_in[6];
  const float* ioux_b   = (const float*)d_in[7];
  const float* iouh_w   = (const float*)d_in[8];
  const float* iouh_b   = (const float*)d_in[9];
  const float* fx_w     = (const float*)d_in[10];
  const float* fx_b     = (const float*)d_in[11];
  const float* fh_w     = (const float*)d_in[12];
  const float* fh_b     = (const float*)d_in[13];
  float* out = (float*)d_out;

  char* ws = (char*)d_ws;
  size_t o = 0;
  auto alloc = [&](size_t bytes){ size_t r = o; o += (bytes + 255) & ~(size_t)255; return r; };
  size_t off_xb    = alloc((size_t)NROWS*KX*2);        // 56 MB bf16 x (padded)
  size_t off_hb    = alloc((size_t)NROWS*H*2);         // 44.8 MB bf16 h
  size_t off_c     = alloc((size_t)NTOT*H*4);          // 89.5 MB fp32 c
  size_t off_WN    = alloc((size_t)1024*KN*2);         // 1.2 MB
  size_t off_WE    = alloc((size_t)NE*512*256*2);      // 9.7 MB
  size_t off_bias  = alloc(1024*4);
  size_t off_ybuf  = alloc((size_t)NLEAF*512*2);       // 67 MB
  size_t off_hroot = alloc(256*4);
  size_t off_perm  = alloc((size_t)(NICH + 8*PERMPAD)*4);
  size_t off_bhist = alloc((size_t)HB*NBINS*4);
  size_t off_boff  = alloc((size_t)HB*NBINS*4);
  size_t off_ptot  = alloc(8*4);

  unsigned short* xb    = (unsigned short*)(ws + off_xb);
  unsigned short* hb    = (unsigned short*)(ws + off_hb);
  float*          c_all = (float*)(ws + off_c);
  unsigned short* WN    = (unsigned short*)(ws + off_WN);
  unsigned short* WE    = (unsigned short*)(ws + off_WE);
  float*          bias  = (float*)(ws + off_bias);
  unsigned short* ybuf  = (unsigned short*)(ws + off_ybuf);
  float*          hroot = (float*)(ws + off_hroot);
  int* perm  = (int*)(ws + off_perm);
  int* bhist = (int*)(ws + off_bhist);
  int* boff  = (int*)(ws + off_boff);
  int* ptot  = (int*)(ws + off_ptot);

  hipMemsetAsync(perm, 0xFF, (size_t)(NICH + 8*PERMPAD)*4, stream);

  k_convx<<<2048, 256, 0, stream>>>(x, xb);
  k_convw<<<2048, 256, 0, stream>>>(ioux_w, fx_w, iouh_w, fh_w, e2h_w, WN, WE);
  k_bias <<<4, 256, 0, stream>>>(ioux_b, iouh_b, fx_b, fh_b, bias);
  k_hist2   <<<HB, 256, 0, stream>>>(edge_type, bhist);
  k_scan    <<<1, 512, 0, stream>>>(bhist, boff, ptot);
  k_scatter2<<<HB, 256, 0, stream>>>(edge_type, boff, perm);

  // leaves: gates = x @ WN[iou]^T + b -> h,c fused  (M=65536, K=320)
  k_leaf_gates<<<dim3(NLEAF/64, 2), 256, 0, stream>>>(xb, WN, bias, c_all, hb);

  // levels 1..8: child GEMM (type-sorted, LDS-staged) + fused gates GEMM
  for (int l=1; l<=8; ++l){
    int s    = h_offs[l];
    int m    = h_offs[l+1] - s;
    int childbase = h_offs[l-1];
    int nch  = s - childbase;
    int nblk = (nch + NE*31 + 31)/32;
    k_gemm_ch<<<nblk, 256, 0, stream>>>(hb, edge_type, perm, ptot, WE, ybuf, l);
    k_gates4<<<dim3((m+63)/64, 2), 256, 0, stream>>>(
        xb + (size_t)s*KX, ybuf, WN, bias,
        c_all + (size_t)childbase*H,
        c_all + (size_t)s*H, hb + (size_t)s*H,
        hroot, (l==8) ? 0 : -1, m);
  }
  k_out<<<1, 256, 0, stream>>>(c_all, hroot, out);
}